// Round 4
// baseline (851.682 us; speedup 1.0000x reference)
//
#include <hip/hip_runtime.h>
#include <hip/hip_bf16.h>
#include <math.h>

#define NTOK 4096   // B*S
#define DDIM 1024
#define HDIM 4096
#define EEXP 8
#define NPAIR_PAD (2*NTOK + EEXP*256)   // 256-padded per-expert segments = 10240

#define BM 256
#define BN 256
#define BK 64

typedef __attribute__((ext_vector_type(8))) short short8;
typedef __attribute__((ext_vector_type(4))) short short4v;
typedef __attribute__((ext_vector_type(4))) float f32x4;

static __device__ __forceinline__ unsigned short f2bf(float f){
  unsigned int u = __float_as_uint(f);
  u += 0x7FFFu + ((u >> 16) & 1u);
  return (unsigned short)(u >> 16);
}

static __device__ __forceinline__ void gload16(const void* g, void* l){
  __builtin_amdgcn_global_load_lds(
      (const __attribute__((address_space(1))) void*)g,
      (__attribute__((address_space(3))) void*)l, 16, 0, 0);
}

// ---- w (f32) -> wb (bf16, pre-swizzled: within each 128B group of 8x16B chunks,
// dest chunk c holds src chunk (c&~7)|((c^row)&7)) ----
__global__ __launch_bounds__(256) void convert_w_kernel(const float* __restrict__ w,
    short* __restrict__ wb, int klog2){
  const int cshift = klog2 - 3;
  size_t i = (size_t)blockIdx.x * 256 + threadIdx.x;   // output chunk index
  size_t n = i >> cshift;
  int c = (int)(i & ((1u << cshift) - 1u));
  int csw = (c & ~7) | ((c ^ (int)n) & 7);
  const float* src = w + (n << klog2) + (size_t)csw * 8;
  f32x4 a = ((const f32x4*)src)[0];
  f32x4 b = ((const f32x4*)src)[1];
  short8 o;
#pragma unroll
  for (int j = 0; j < 4; ++j){ o[j] = (short)f2bf(a[j]); o[j+4] = (short)f2bf(b[j]); }
  *(short8*)(wb + (n << klog2) + (size_t)c * 8) = o;
}

// ---- gate: logits, top-2, softmax; emits xb (bf16 x) and bias-init of out ----
__global__ __launch_bounds__(256) void gate_kernel(const float* __restrict__ x,
    const float* __restrict__ gw, const float* __restrict__ gb,
    const float* __restrict__ b2, float* __restrict__ outF,
    short* __restrict__ xb, int2* __restrict__ te, float2* __restrict__ tw,
    int* __restrict__ cnt){
  const int t = blockIdx.x * 4 + (threadIdx.x >> 6);
  const int l = threadIdx.x & 63;
  const f32x4* xr = (const f32x4*)(x + (size_t)t * DDIM);
  f32x4 xv[4];
#pragma unroll
  for (int j = 0; j < 4; ++j) xv[j] = xr[l + 64*j];
#pragma unroll
  for (int j = 0; j < 4; ++j){
    short4v o;
#pragma unroll
    for (int q = 0; q < 4; ++q) o[q] = (short)f2bf(xv[j][q]);
    ((short4v*)(xb + (size_t)t * DDIM))[l + 64*j] = o;
  }
  float acc[EEXP];
#pragma unroll
  for (int e = 0; e < EEXP; ++e) acc[e] = 0.f;
#pragma unroll
  for (int j = 0; j < 4; ++j){
#pragma unroll
    for (int e = 0; e < EEXP; ++e){
      f32x4 gv = ((const f32x4*)(gw + (size_t)e*DDIM))[l + 64*j];
      acc[e] += xv[j][0]*gv[0] + xv[j][1]*gv[1] + xv[j][2]*gv[2] + xv[j][3]*gv[3];
    }
  }
#pragma unroll
  for (int e = 0; e < EEXP; ++e){
#pragma unroll
    for (int off = 32; off > 0; off >>= 1) acc[e] += __shfl_xor(acc[e], off);
  }
  float lg[EEXP];
#pragma unroll
  for (int e = 0; e < EEXP; ++e) lg[e] = acc[e] + gb[e];
  int e0 = 0; float v0 = lg[0];
#pragma unroll
  for (int e = 1; e < EEXP; ++e) if (lg[e] > v0){ v0 = lg[e]; e0 = e; }
  int e1 = -1; float v1 = -1e30f;
#pragma unroll
  for (int e = 0; e < EEXP; ++e) if (e != e0 && lg[e] > v1){ v1 = lg[e]; e1 = e; }
  float r  = expf(v1 - v0);
  float w0 = 1.f / (1.f + r);
  float w1 = r  / (1.f + r);
  if (l == 0){
    outF[(size_t)NTOK*DDIM + 2*t    ] = (float)e0;
    outF[(size_t)NTOK*DDIM + 2*t + 1] = (float)e1;
    te[t] = make_int2(e0, e1);
    tw[t] = make_float2(w0, w1);
    atomicAdd(&cnt[e0], 1);
    atomicAdd(&cnt[e1], 1);
  }
  const f32x4* r0 = (const f32x4*)(b2 + (size_t)e0 * DDIM);
  const f32x4* r1 = (const f32x4*)(b2 + (size_t)e1 * DDIM);
  f32x4* orow = (f32x4*)(outF + (size_t)t * DDIM);
#pragma unroll
  for (int j = 0; j < 4; ++j){
    f32x4 a = r0[l + 64*j], b = r1[l + 64*j], o;
#pragma unroll
    for (int q = 0; q < 4; ++q) o[q] = w0 * a[q] + w1 * b[q];
    orow[l + 64*j] = o;
  }
}

__global__ void scan_kernel(const int* __restrict__ cnt, int* __restrict__ offs){
  if (threadIdx.x == 0){
    int s = 0;
    for (int e = 0; e < EEXP; ++e){ offs[e] = s; s += (cnt[e] + 255) & ~255; }
  }
}

__global__ __launch_bounds__(256) void scatter_kernel(const int2* __restrict__ te,
    const float2* __restrict__ tw, const int* __restrict__ offs,
    int* __restrict__ cur, int* __restrict__ tokp, float* __restrict__ wtp){
  int t = blockIdx.x * blockDim.x + threadIdx.x;
  if (t >= NTOK) return;
  int2 e = te[t]; float2 w = tw[t];
  int p0 = offs[e.x] + atomicAdd(&cur[e.x], 1);
  tokp[p0] = t; wtp[p0] = w.x;
  int p1 = offs[e.y] + atomicAdd(&cur[e.y], 1);
  tokp[p1] = t; wtp[p1] = w.y;
}

// ---- gather x rows into compact pair order, pre-swizzled (chunk c <- src chunk c^(row&7)) ----
__global__ __launch_bounds__(256) void gather_x_kernel(const short* __restrict__ xb,
    const int* __restrict__ tokp, short* __restrict__ xg){
  const int rowp = blockIdx.x * 4 + (threadIdx.x >> 6);
  const int l = threadIdx.x & 63;
  const short* src = xb + (size_t)tokp[rowp] * DDIM;
  short* dst = xg + (size_t)rowp * DDIM;
#pragma unroll
  for (int p = 0; p < 2; ++p){
    int c = p * 64 + l;
    int cs = (c & ~7) | ((c ^ rowp) & 7);
    *(short8*)(dst + c * 8) = *(const short8*)(src + cs * 8);
  }
}

// ---- grouped GEMM: 256x256, BK=64, 8 waves, 128KB LDS dbuf, counted-vmcnt pipeline ----
// PHASE 1: h = GELU(xg @ w1b^T + b1)  (h written pre-swizzled)
// PHASE 2: out += wt * (h @ w2b^T)    (K-split 2, atomic accumulate; bias pre-folded by gate)
template<int PHASE, int KDIM, int NDIM, int KSPLIT, int GMl>
__global__ __launch_bounds__(512, 1) void moe_gemm(
    const short* __restrict__ Ab, const short* __restrict__ Wb,
    const float* __restrict__ bias,
    const int* __restrict__ cnts, const int* __restrict__ offs,
    const int* __restrict__ tokp, const float* __restrict__ wtp,
    short* __restrict__ Hout, float* __restrict__ Out){
  constexpr int GN = NDIM / BN;
  constexpr int KLEN = KDIM / KSPLIT;
  constexpr int NK = KLEN / BK;
  const int e = blockIdx.x & 7;              // expert == XCD
  int i = blockIdx.x >> 3;
  int ks = 0;
  if (KSPLIT > 1){ ks = i / (GMl * GN); i -= ks * (GMl * GN); }
  const int mb0 = i % GMl;
  const int n0  = (i / GMl) * BN;
  const int cnt = cnts[e];
  const int off = offs[e];
  const int kbase = ks * KLEN;

  __shared__ short As[2][BM * BK];   // 32KB x2
  __shared__ short Bs[2][BM * BK];   // 32KB x2  -> 128KB total

  const int tid  = threadIdx.x;
  const int lane = tid & 63;
  const int wid  = tid >> 6;
  const int wr   = wid >> 2;   // 0..1 -> 128 rows
  const int wc   = wid & 3;    // 0..3 -> 64 cols

  const short* wE = Wb + (size_t)e * NDIM * KDIM;
  size_t bSrc[4]; int ldsOff[4];
#pragma unroll
  for (int s = 0; s < 4; ++s){
    const int rb = wid * 8 + s * 64;          // wave-uniform base row (8 rows x 128B = 1KB/wave)
    ldsOff[s] = rb * BK;                      // shorts; HW adds lane*16B
    const int r = rb + (lane >> 3);
    bSrc[s] = (size_t)(n0 + r) * KDIM + kbase + (lane & 7) * 8;   // wb pre-swizzled
  }

  for (int m0 = mb0 * BM; m0 < cnt; m0 += GMl * BM){
    const int mrows = min(BM, cnt - m0);
    size_t aSrc[4];
#pragma unroll
    for (int s = 0; s < 4; ++s){
      const int r = wid * 8 + s * 64 + (lane >> 3);
      aSrc[s] = (size_t)(off + m0 + r) * KDIM + kbase + (lane & 7) * 8;  // pre-swizzled
    }

    f32x4 acc[8][4];
#pragma unroll
    for (int ii = 0; ii < 8; ++ii)
#pragma unroll
      for (int j = 0; j < 4; ++j) acc[ii][j] = (f32x4){0.f, 0.f, 0.f, 0.f};

    auto STAGE = [&](int buf, int t){
      const int k0 = t * BK;
#pragma unroll
      for (int s = 0; s < 4; ++s) gload16(Ab + aSrc[s] + k0, &As[buf][ldsOff[s]]);
#pragma unroll
      for (int s = 0; s < 4; ++s) gload16(wE + bSrc[s] + k0, &Bs[buf][ldsOff[s]]);
    };
    auto COMPUTE = [&](int buf){
#pragma unroll
      for (int kk = 0; kk < 2; ++kk){
        short8 af[8], bf[4];
        const int bc = kk * 64 + (lane >> 4) * 16;
#pragma unroll
        for (int ii = 0; ii < 8; ++ii){
          const int rA = wr * 128 + ii * 16 + (lane & 15);
          af[ii] = *(const short8*)&As[buf][rA * BK + ((bc ^ ((rA & 7) << 4)) >> 1)];
        }
#pragma unroll
        for (int j = 0; j < 4; ++j){
          const int rB = wc * 64 + j * 16 + (lane & 15);
          bf[j] = *(const short8*)&Bs[buf][rB * BK + ((bc ^ ((rB & 7) << 4)) >> 1)];
        }
        __builtin_amdgcn_s_setprio(1);
#pragma unroll
        for (int ii = 0; ii < 8; ++ii)
#pragma unroll
          for (int j = 0; j < 4; ++j)
            acc[ii][j] = __builtin_amdgcn_mfma_f32_16x16x32_bf16(af[ii], bf[j], acc[ii][j], 0, 0, 0);
        __builtin_amdgcn_s_setprio(0);
      }
    };

    STAGE(0, 0);
    int cur = 0;
    for (int t = 0; t < NK - 1; ++t){
      STAGE(cur ^ 1, t + 1);                       // 8 loads issued; stay in flight
      asm volatile("s_waitcnt vmcnt(8)" ::: "memory");   // tile t fully landed (8 newest = t+1)
      __builtin_amdgcn_s_barrier();
      __builtin_amdgcn_sched_barrier(0);
      COMPUTE(cur);
      __builtin_amdgcn_sched_barrier(0);
      __builtin_amdgcn_s_barrier();                // readers done -> buf reusable
      cur ^= 1;
    }
    asm volatile("s_waitcnt vmcnt(0)" ::: "memory");
    __builtin_amdgcn_s_barrier();
    __builtin_amdgcn_sched_barrier(0);
    COMPUTE(cur);
    __builtin_amdgcn_sched_barrier(0);
    __builtin_amdgcn_s_barrier();

    if (PHASE == 1){
#pragma unroll
      for (int j = 0; j < 4; ++j){
        const int n = n0 + wc * 64 + j * 16 + (lane & 15);
        const float bv = bias[(size_t)e * NDIM + n];
#pragma unroll
        for (int ii = 0; ii < 8; ++ii){
#pragma unroll
          for (int q = 0; q < 4; ++q){
            const int lm = wr * 128 + ii * 16 + (lane >> 4) * 4 + q;
            if (lm < mrows){
              float v = acc[ii][j][q] + bv;
              v = 0.5f * v * (1.0f + erff(v * 0.70710678118654752f));  // exact GELU
              const int nsw = n ^ ((lm & 7) << 3);                      // pre-swizzle h
              Hout[(size_t)(off + m0 + lm) * NDIM + nsw] = (short)f2bf(v);
            }
          }
        }
      }
    } else {
#pragma unroll
      for (int j = 0; j < 4; ++j){
        const int n = n0 + wc * 64 + j * 16 + (lane & 15);
#pragma unroll
        for (int ii = 0; ii < 8; ++ii){
#pragma unroll
          for (int q = 0; q < 4; ++q){
            const int lm = wr * 128 + ii * 16 + (lane >> 4) * 4 + q;
            if (lm < mrows){
              const int p = off + m0 + lm;
              atomicAdd(&Out[(size_t)tokp[p] * NDIM + n], wtp[p] * acc[ii][j][q]);
            }
          }
        }
      }
    }
  }
}

extern "C" void kernel_launch(void* const* d_in, const int* in_sizes, int n_in,
                              void* d_out, int out_size, void* d_ws, size_t ws_size,
                              hipStream_t stream){
  const float* x  = (const float*)d_in[0];
  const float* gw = (const float*)d_in[1];
  const float* gb = (const float*)d_in[2];
  const float* w1 = (const float*)d_in[3];
  const float* b1 = (const float*)d_in[4];
  const float* w2 = (const float*)d_in[5];
  const float* b2 = (const float*)d_in[6];
  float* outF = (float*)d_out;

  char* p = (char*)d_ws;
  short* xb = (short*)p;  p += (size_t)NTOK * DDIM * 2;          // 8.4 MB
  short* xg = (short*)p;  p += (size_t)NPAIR_PAD * DDIM * 2;     // 21 MB (gathered, pre-swizzled)
  short* h  = (short*)p;  p += (size_t)NPAIR_PAD * HDIM * 2;     // 83.9 MB (pre-swizzled bf16)
  short* wb = (short*)p;  p += (size_t)EEXP * HDIM * DDIM * 2;   // 67.1 MB (w1b then w2b)
  int*   tokp = (int*)p;  p += (size_t)NPAIR_PAD * 4;
  float* wtp  = (float*)p;p += (size_t)NPAIR_PAD * 4;
  int2*  te   = (int2*)p; p += (size_t)NTOK * 8;
  float2* tw  = (float2*)p; p += (size_t)NTOK * 8;
  int* meta = (int*)p;    // cnt[8] | offs[8] | cur[8]
  int* cnt  = meta;
  int* offs = meta + 8;
  int* cur  = meta + 16;

  hipMemsetAsync(meta, 0, 24 * sizeof(int), stream);
  hipMemsetAsync(tokp, 0, (size_t)NPAIR_PAD * 4, stream);   // padded slots -> token 0 (benign)
  gate_kernel<<<NTOK / 4, 256, 0, stream>>>(x, gw, gb, b2, outF, xb, te, tw, cnt);
  scan_kernel<<<1, 64, 0, stream>>>(cnt, offs);
  scatter_kernel<<<(NTOK + 255) / 256, 256, 0, stream>>>(te, tw, offs, cur, tokp, wtp);
  gather_x_kernel<<<NPAIR_PAD / 4, 256, 0, stream>>>(xb, tokp, xg);
  convert_w_kernel<<<16384, 256, 0, stream>>>(w1, wb, 10);
  moe_gemm<1, DDIM, HDIM, 1, 4><<<EEXP * 4 * (HDIM / BN), 512, 0, stream>>>(
      xg, wb, b1, cnt, offs, tokp, wtp, h, nullptr);
  convert_w_kernel<<<16384, 256, 0, stream>>>(w2, wb, 12);
  moe_gemm<2, HDIM, DDIM, 2, 4><<<EEXP * 4 * (DDIM / BN) * 2, 512, 0, stream>>>(
      h, wb, nullptr, cnt, offs, tokp, wtp, nullptr, outF);
}

// Round 5
// 539.668 us; speedup vs baseline: 1.5782x; 1.5782x over previous
//
#include <hip/hip_runtime.h>
#include <hip/hip_bf16.h>
#include <math.h>

#define NTOK 4096   // B*S
#define DDIM 1024
#define HDIM 4096
#define EEXP 8
#define NPAIR_PAD (2*NTOK + EEXP*256)   // 10240 (256-padded per-expert segments)
#define MAXT (NPAIR_PAD / 256)          // 40 max m-tiles

#define BM 256
#define BN 256
#define BK 64

typedef __attribute__((ext_vector_type(8))) short short8;
typedef __attribute__((ext_vector_type(4))) short short4v;
typedef __attribute__((ext_vector_type(4))) float f32x4;

static __device__ __forceinline__ unsigned short f2bf(float f){
  unsigned int u = __float_as_uint(f);
  u += 0x7FFFu + ((u >> 16) & 1u);
  return (unsigned short)(u >> 16);
}
static __device__ __forceinline__ float bf2f(short s){
  return __uint_as_float(((unsigned int)(unsigned short)s) << 16);
}
static __device__ __forceinline__ void gload16(const void* g, void* l){
  __builtin_amdgcn_global_load_lds(
      (const __attribute__((address_space(1))) void*)g,
      (__attribute__((address_space(3))) void*)l, 16, 0, 0);
}

// ---- w (f32) -> wb (bf16, pre-swizzled: within each 8x16B chunk group,
// dest chunk c holds src chunk (c&~7)|((c^row)&7)) ----
__global__ __launch_bounds__(256) void convert_w_kernel(const float* __restrict__ w,
    short* __restrict__ wb, int klog2){
  const int cshift = klog2 - 3;
  size_t i = (size_t)blockIdx.x * 256 + threadIdx.x;
  size_t n = i >> cshift;
  int c = (int)(i & ((1u << cshift) - 1u));
  int csw = (c & ~7) | ((c ^ (int)n) & 7);
  const float* src = w + (n << klog2) + (size_t)csw * 8;
  f32x4 a = ((const f32x4*)src)[0];
  f32x4 b = ((const f32x4*)src)[1];
  short8 o;
#pragma unroll
  for (int j = 0; j < 4; ++j){ o[j] = (short)f2bf(a[j]); o[j+4] = (short)f2bf(b[j]); }
  *(short8*)(wb + (n << klog2) + (size_t)c * 8) = o;
}

// ---- gate: logits, top-2, softmax; emits xb (bf16 x) and 'selected' tail ----
__global__ __launch_bounds__(256) void gate_kernel(const float* __restrict__ x,
    const float* __restrict__ gw, const float* __restrict__ gb,
    float* __restrict__ outF, short* __restrict__ xb,
    int2* __restrict__ te, float2* __restrict__ tw, int* __restrict__ cnt){
  const int t = blockIdx.x * 4 + (threadIdx.x >> 6);
  const int l = threadIdx.x & 63;
  const f32x4* xr = (const f32x4*)(x + (size_t)t * DDIM);
  f32x4 xv[4];
#pragma unroll
  for (int j = 0; j < 4; ++j) xv[j] = xr[l + 64*j];
#pragma unroll
  for (int j = 0; j < 4; ++j){
    short4v o;
#pragma unroll
    for (int q = 0; q < 4; ++q) o[q] = (short)f2bf(xv[j][q]);
    ((short4v*)(xb + (size_t)t * DDIM))[l + 64*j] = o;
  }
  float acc[EEXP];
#pragma unroll
  for (int e = 0; e < EEXP; ++e) acc[e] = 0.f;
#pragma unroll
  for (int j = 0; j < 4; ++j){
#pragma unroll
    for (int e = 0; e < EEXP; ++e){
      f32x4 gv = ((const f32x4*)(gw + (size_t)e*DDIM))[l + 64*j];
      acc[e] += xv[j][0]*gv[0] + xv[j][1]*gv[1] + xv[j][2]*gv[2] + xv[j][3]*gv[3];
    }
  }
#pragma unroll
  for (int e = 0; e < EEXP; ++e){
#pragma unroll
    for (int off = 32; off > 0; off >>= 1) acc[e] += __shfl_xor(acc[e], off);
  }
  if (l == 0){
    float lg[EEXP];
#pragma unroll
    for (int e = 0; e < EEXP; ++e) lg[e] = acc[e] + gb[e];
    int e0 = 0; float v0 = lg[0];
#pragma unroll
    for (int e = 1; e < EEXP; ++e) if (lg[e] > v0){ v0 = lg[e]; e0 = e; }
    int e1 = -1; float v1 = -1e30f;
#pragma unroll
    for (int e = 0; e < EEXP; ++e) if (e != e0 && lg[e] > v1){ v1 = lg[e]; e1 = e; }
    float r  = expf(v1 - v0);
    float w0 = 1.f / (1.f + r);
    float w1 = r  / (1.f + r);
    outF[(size_t)NTOK*DDIM + 2*t    ] = (float)e0;
    outF[(size_t)NTOK*DDIM + 2*t + 1] = (float)e1;
    te[t] = make_int2(e0, e1);
    tw[t] = make_float2(w0, w1);
    atomicAdd(&cnt[e0], 1);
    atomicAdd(&cnt[e1], 1);
  }
}

// meta: [0:8) cnt | [8:16) offs | [16:24) cur | [24] ntiles | [32:72) tileE | [72:112) tileM
__global__ void scan_kernel(int* __restrict__ meta){
  if (threadIdx.x == 0){
    int s = 0, nt = 0;
    for (int e = 0; e < EEXP; ++e){
      meta[8+e] = s;
      int c = meta[e];
      int tiles = (c + 255) >> 8;
      for (int i = 0; i < tiles; ++i){ meta[32+nt] = e; meta[72+nt] = i * 256; ++nt; }
      s += (c + 255) & ~255;
    }
    meta[24] = nt;
  }
}

__global__ __launch_bounds__(256) void scatter_kernel(const int2* __restrict__ te,
    const int* __restrict__ offs, int* __restrict__ cur,
    int* __restrict__ tokp, int* __restrict__ pidx){
  int t = blockIdx.x * blockDim.x + threadIdx.x;
  if (t >= NTOK) return;
  int2 e = te[t];
  int p0 = offs[e.x] + atomicAdd(&cur[e.x], 1);
  tokp[p0] = t; pidx[2*t] = p0;
  int p1 = offs[e.y] + atomicAdd(&cur[e.y], 1);
  tokp[p1] = t; pidx[2*t+1] = p1;
}

// ---- gather x rows into compact pair order, pre-swizzled (chunk c <- src chunk c^(row&7)) ----
__global__ __launch_bounds__(256) void gather_x_kernel(const short* __restrict__ xb,
    const int* __restrict__ tokp, short* __restrict__ xg){
  const int rowp = blockIdx.x * 4 + (threadIdx.x >> 6);
  const int l = threadIdx.x & 63;
  const short* src = xb + (size_t)tokp[rowp] * DDIM;
  short* dst = xg + (size_t)rowp * DDIM;
#pragma unroll
  for (int p = 0; p < 2; ++p){
    int c = p * 64 + l;
    int cs = (c & ~7) | ((c ^ rowp) & 7);
    *(short8*)(dst + c * 8) = *(const short8*)(src + cs * 8);
  }
}

// ---- grouped GEMM: 256x256xBK64, 8 waves, counted-vmcnt dbuf, LDS-transposed epilogue ----
// PHASE 1: h = GELU(xg @ w1b^T + b1)  -> bf16, pre-swizzled, coalesced short8 stores
// PHASE 2: y[ks] = h @ w2b^T (K-split halves, unweighted) -> bf16, linear, coalesced
template<int PHASE, int KDIM, int NDIM, int KSPLIT>
__global__ __launch_bounds__(512, 1) void moe_gemm(
    const short* __restrict__ Ab, const short* __restrict__ Wb,
    const float* __restrict__ bias, const int* __restrict__ meta,
    short* __restrict__ O0, short* __restrict__ O1){
  constexpr int NB = NDIM / BN;
  constexpr int KLEN = KDIM / KSPLIT;
  constexpr int NK = KLEN / BK;
  // XCD-chunked bijective mapping: each XCD gets contiguous logical chunk,
  // tile-fastest so same-XCD blocks share the B-panel.
  const int cpx = gridDim.x >> 3;
  const int lid = (blockIdx.x & 7) * cpx + (blockIdx.x >> 3);
  const int tile = lid % MAXT;
  const int rest = lid / MAXT;
  if (tile >= meta[24]) return;
  const int n0 = (rest % NB) * BN;
  const int ks = rest / NB;
  const int e   = meta[32 + tile];
  const int m0  = meta[72 + tile];
  const int cnt = meta[e];
  const int off = meta[8 + e];
  const int mrows = min(BM, cnt - m0);
  const int kbase = ks * KLEN;
  short* O = ks ? O1 : O0;

  __shared__ __align__(16) short SMEM[4][BM * BK];   // As=SMEM[buf], Bs=SMEM[2+buf]; 128KB

  const int tid  = threadIdx.x;
  const int lane = tid & 63;
  const int wid  = tid >> 6;
  const int wr   = wid >> 2;   // 0..1 -> 128 rows
  const int wc   = wid & 3;    // 0..3 -> 64 cols

  const short* wE = Wb + (size_t)e * NDIM * KDIM;
  size_t aSrc[4], bSrc[4]; int ldsOff[4];
#pragma unroll
  for (int s = 0; s < 4; ++s){
    const int rb = wid * 8 + s * 64;
    ldsOff[s] = rb * BK;                        // wave-uniform; HW adds lane*16B
    const int r = rb + (lane >> 3);
    aSrc[s] = (size_t)(off + m0 + r) * KDIM + kbase + (lane & 7) * 8;  // pre-swizzled
    bSrc[s] = (size_t)(n0 + r) * KDIM + kbase + (lane & 7) * 8;        // pre-swizzled
  }

  f32x4 acc[8][4];
#pragma unroll
  for (int ii = 0; ii < 8; ++ii)
#pragma unroll
    for (int j = 0; j < 4; ++j) acc[ii][j] = (f32x4){0.f, 0.f, 0.f, 0.f};

  auto STAGE = [&](int buf, int t){
    const int k0 = t * BK;
    short* As = SMEM[buf];
    short* Bs = SMEM[2 + buf];
#pragma unroll
    for (int s = 0; s < 4; ++s) gload16(Ab + aSrc[s] + k0, &As[ldsOff[s]]);
#pragma unroll
    for (int s = 0; s < 4; ++s) gload16(wE + bSrc[s] + k0, &Bs[ldsOff[s]]);
  };
  auto COMPUTE = [&](int buf){
    const short* As = SMEM[buf];
    const short* Bs = SMEM[2 + buf];
#pragma unroll
    for (int kk = 0; kk < 2; ++kk){
      short8 af[8], bf[4];
      const int bc = kk * 64 + (lane >> 4) * 16;
#pragma unroll
      for (int ii = 0; ii < 8; ++ii){
        const int rA = wr * 128 + ii * 16 + (lane & 15);
        af[ii] = *(const short8*)&As[rA * BK + ((bc ^ ((rA & 7) << 4)) >> 1)];
      }
#pragma unroll
      for (int j = 0; j < 4; ++j){
        const int rB = wc * 64 + j * 16 + (lane & 15);
        bf[j] = *(const short8*)&Bs[rB * BK + ((bc ^ ((rB & 7) << 4)) >> 1)];
      }
      __builtin_amdgcn_s_setprio(1);
#pragma unroll
      for (int ii = 0; ii < 8; ++ii)
#pragma unroll
        for (int j = 0; j < 4; ++j)
          acc[ii][j] = __builtin_amdgcn_mfma_f32_16x16x32_bf16(af[ii], bf[j], acc[ii][j], 0, 0, 0);
      __builtin_amdgcn_s_setprio(0);
    }
  };

  STAGE(0, 0);
  int cur = 0;
  for (int t = 0; t < NK - 1; ++t){
    STAGE(cur ^ 1, t + 1);                            // 8 loads stay in flight
    asm volatile("s_waitcnt vmcnt(8)" ::: "memory");  // tile t landed (newest 8 = t+1)
    __builtin_amdgcn_s_barrier();
    asm volatile("" ::: "memory");
    COMPUTE(cur);
    asm volatile("" ::: "memory");
    __builtin_amdgcn_s_barrier();
    asm volatile("" ::: "memory");
    cur ^= 1;
  }
  asm volatile("s_waitcnt vmcnt(0)" ::: "memory");
  __builtin_amdgcn_s_barrier();
  asm volatile("" ::: "memory");
  COMPUTE(cur);
  __syncthreads();               // all LDS reads done -> reuse as transpose buffer

  // ---- epilogue: acc -> LDS (bank-swizzled bf16 256x256 tile) -> coalesced stores ----
  short* T = &SMEM[0][0];
#pragma unroll
  for (int j = 0; j < 4; ++j){
    const int n = n0 + wc * 64 + j * 16 + (lane & 15);
    const float bv = (PHASE == 1) ? bias[(size_t)e * NDIM + n] : 0.f;
#pragma unroll
    for (int ii = 0; ii < 8; ++ii){
#pragma unroll
      for (int q = 0; q < 4; ++q){
        const int r = wr * 128 + ii * 16 + (lane >> 4) * 4 + q;
        const int c = wc * 64 + j * 16 + (lane & 15);
        float v = acc[ii][j][q];
        if (PHASE == 1){
          v += bv;
          v = 0.5f * v * (1.0f + erff(v * 0.70710678118654752f));  // exact GELU
        }
        T[r * 256 + (c ^ ((r & 7) << 3))] = (short)f2bf(v);
      }
    }
  }
  __syncthreads();
  {
    const int r = tid >> 1;
    const int key = r & 7;
    const size_t rowb = (size_t)(off + m0 + r) * NDIM + n0;
#pragma unroll
    for (int c8 = 0; c8 < 16; ++c8){
      const int pc = (tid & 1) * 16 + (c8 ^ key);          // phys chunk (bank-spread read)
      short8 v = *(const short8*)&T[r * 256 + pc * 8];
      // PHASE1: store phys chunk pc (content pre-swizzled for GEMM2 staging).
      // PHASE2: content of phys pc is true chunk (tid&1)*16+c8 -> y stays linear.
      const int gcc = (PHASE == 1) ? pc : ((tid & 1) * 16 + c8);
      if (r < mrows) *(short8*)&O[rowb + gcc * 8] = v;
    }
  }
}

// ---- combine: out[t] = w0*(y0[p0]+y1[p0]+b2[e0]) + w1*(y0[p1]+y1[p1]+b2[e1]) ----
__global__ __launch_bounds__(256) void combine_kernel(
    const short* __restrict__ y0, const short* __restrict__ y1,
    const int2* __restrict__ te, const float2* __restrict__ tw,
    const int* __restrict__ pidx, const float* __restrict__ b2,
    float* __restrict__ outF){
  const int t = blockIdx.x;
  const int d = threadIdx.x * 4;
  int2 e = te[t]; float2 w = tw[t];
  int p0 = pidx[2*t], p1 = pidx[2*t+1];
  short4v a0 = *(const short4v*)&y0[(size_t)p0 * DDIM + d];
  short4v a1 = *(const short4v*)&y1[(size_t)p0 * DDIM + d];
  short4v c0 = *(const short4v*)&y0[(size_t)p1 * DDIM + d];
  short4v c1 = *(const short4v*)&y1[(size_t)p1 * DDIM + d];
  f32x4 b0 = *(const f32x4*)&b2[(size_t)e.x * DDIM + d];
  f32x4 b1 = *(const f32x4*)&b2[(size_t)e.y * DDIM + d];
  f32x4 o;
#pragma unroll
  for (int q = 0; q < 4; ++q){
    float s0 = bf2f(a0[q]) + bf2f(a1[q]) + b0[q];
    float s1 = bf2f(c0[q]) + bf2f(c1[q]) + b1[q];
    o[q] = w.x * s0 + w.y * s1;
  }
  *(f32x4*)&outF[(size_t)t * DDIM + d] = o;
}

extern "C" void kernel_launch(void* const* d_in, const int* in_sizes, int n_in,
                              void* d_out, int out_size, void* d_ws, size_t ws_size,
                              hipStream_t stream){
  const float* x  = (const float*)d_in[0];
  const float* gw = (const float*)d_in[1];
  const float* gb = (const float*)d_in[2];
  const float* w1 = (const float*)d_in[3];
  const float* b1 = (const float*)d_in[4];
  const float* w2 = (const float*)d_in[5];
  const float* b2 = (const float*)d_in[6];
  float* outF = (float*)d_out;

  char* p = (char*)d_ws;
  short* xb = (short*)p;  p += (size_t)NTOK * DDIM * 2;          // 8.4 MB
  short* xg = (short*)p;  p += (size_t)NPAIR_PAD * DDIM * 2;     // 21 MB; reused as y0
  short* h  = (short*)p;  p += (size_t)NPAIR_PAD * HDIM * 2;     // 83.9 MB
  short* wb = (short*)p;  p += (size_t)EEXP * HDIM * DDIM * 2;   // 67.1 MB (w1b then w2b)
  short* y1 = (short*)p;  p += (size_t)NPAIR_PAD * DDIM * 2;     // 21 MB
  int*   tokp = (int*)p;  p += (size_t)NPAIR_PAD * 4;
  int*   pidx = (int*)p;  p += (size_t)2 * NTOK * 4;
  int2*  te   = (int2*)p; p += (size_t)NTOK * 8;
  float2* tw  = (float2*)p; p += (size_t)NTOK * 8;
  int* meta = (int*)p;
  short* y0 = xg;

  hipMemsetAsync(meta, 0, 24 * sizeof(int), stream);
  hipMemsetAsync(tokp, 0, (size_t)NPAIR_PAD * 4, stream);
  gate_kernel<<<NTOK / 4, 256, 0, stream>>>(x, gw, gb, outF, xb, te, tw, meta);
  scan_kernel<<<1, 64, 0, stream>>>(meta);
  scatter_kernel<<<(NTOK + 255) / 256, 256, 0, stream>>>(te, meta + 8, meta + 16, tokp, pidx);
  gather_x_kernel<<<NPAIR_PAD / 4, 256, 0, stream>>>(xb, tokp, xg);
  convert_w_kernel<<<16384, 256, 0, stream>>>(w1, wb, 10);
  moe_gemm<1, DDIM, HDIM, 1><<<MAXT * (HDIM / BN), 512, 0, stream>>>(
      xg, wb, b1, meta, h, h);
  convert_w_kernel<<<16384, 256, 0, stream>>>(w2, wb, 12);
  moe_gemm<2, HDIM, DDIM, 2><<<MAXT * (DDIM / BN) * 2, 512, 0, stream>>>(
      h, wb, nullptr, meta, y0, y1);
  combine_kernel<<<NTOK, 256, 0, stream>>>(y0, y1, te, tw, pidx, b2, outF);
}

// Round 6
// 509.569 us; speedup vs baseline: 1.6714x; 1.0591x over previous
//
#include <hip/hip_runtime.h>
#include <hip/hip_bf16.h>
#include <math.h>

#define NTOK 4096   // B*S
#define DDIM 1024
#define HDIM 4096
#define EEXP 8
#define NPAIR_PAD (2*NTOK + EEXP*256)   // 10240 (256-padded per-expert segments)
#define MAXT (NPAIR_PAD / 256)          // 40 max m-tiles

#define BM 256
#define BN 256
#define BK 64

typedef __attribute__((ext_vector_type(8))) short short8;
typedef __attribute__((ext_vector_type(4))) short short4v;
typedef __attribute__((ext_vector_type(4))) float f32x4;

static __device__ __forceinline__ unsigned short f2bf(float f){
  unsigned int u = __float_as_uint(f);
  u += 0x7FFFu + ((u >> 16) & 1u);
  return (unsigned short)(u >> 16);
}
static __device__ __forceinline__ float bf2f(short s){
  return __uint_as_float(((unsigned int)(unsigned short)s) << 16);
}
static __device__ __forceinline__ void gload16(const void* g, void* l){
  __builtin_amdgcn_global_load_lds(
      (const __attribute__((address_space(1))) void*)g,
      (__attribute__((address_space(3))) void*)l, 16, 0, 0);
}
static __device__ __forceinline__ void BAR(){
  asm volatile("" ::: "memory");
  __builtin_amdgcn_s_barrier();
  asm volatile("" ::: "memory");
}

// ---- w (f32) -> wb (bf16, pre-swizzled: dest 16B chunk c holds src chunk (c&~7)|((c^row)&7)) ----
__global__ __launch_bounds__(256) void convert_w_kernel(const float* __restrict__ w,
    short* __restrict__ wb, int klog2){
  const int cshift = klog2 - 3;
  size_t i = (size_t)blockIdx.x * 256 + threadIdx.x;
  size_t n = i >> cshift;
  int c = (int)(i & ((1u << cshift) - 1u));
  int csw = (c & ~7) | ((c ^ (int)n) & 7);
  const float* src = w + (n << klog2) + (size_t)csw * 8;
  f32x4 a = ((const f32x4*)src)[0];
  f32x4 b = ((const f32x4*)src)[1];
  short8 o;
#pragma unroll
  for (int j = 0; j < 4; ++j){ o[j] = (short)f2bf(a[j]); o[j+4] = (short)f2bf(b[j]); }
  *(short8*)(wb + (n << klog2) + (size_t)c * 8) = o;
}

// ---- gate: logits, top-2, softmax; emits xb (bf16 x) and 'selected' tail ----
__global__ __launch_bounds__(256) void gate_kernel(const float* __restrict__ x,
    const float* __restrict__ gw, const float* __restrict__ gb,
    float* __restrict__ outF, short* __restrict__ xb,
    int2* __restrict__ te, float2* __restrict__ tw, int* __restrict__ cnt){
  const int t = blockIdx.x * 4 + (threadIdx.x >> 6);
  const int l = threadIdx.x & 63;
  const f32x4* xr = (const f32x4*)(x + (size_t)t * DDIM);
  f32x4 xv[4];
#pragma unroll
  for (int j = 0; j < 4; ++j) xv[j] = xr[l + 64*j];
#pragma unroll
  for (int j = 0; j < 4; ++j){
    short4v o;
#pragma unroll
    for (int q = 0; q < 4; ++q) o[q] = (short)f2bf(xv[j][q]);
    ((short4v*)(xb + (size_t)t * DDIM))[l + 64*j] = o;
  }
  float acc[EEXP];
#pragma unroll
  for (int e = 0; e < EEXP; ++e) acc[e] = 0.f;
#pragma unroll
  for (int j = 0; j < 4; ++j){
#pragma unroll
    for (int e = 0; e < EEXP; ++e){
      f32x4 gv = ((const f32x4*)(gw + (size_t)e*DDIM))[l + 64*j];
      acc[e] += xv[j][0]*gv[0] + xv[j][1]*gv[1] + xv[j][2]*gv[2] + xv[j][3]*gv[3];
    }
  }
#pragma unroll
  for (int e = 0; e < EEXP; ++e){
#pragma unroll
    for (int off = 32; off > 0; off >>= 1) acc[e] += __shfl_xor(acc[e], off);
  }
  if (l == 0){
    float lg[EEXP];
#pragma unroll
    for (int e = 0; e < EEXP; ++e) lg[e] = acc[e] + gb[e];
    int e0 = 0; float v0 = lg[0];
#pragma unroll
    for (int e = 1; e < EEXP; ++e) if (lg[e] > v0){ v0 = lg[e]; e0 = e; }
    int e1 = -1; float v1 = -1e30f;
#pragma unroll
    for (int e = 0; e < EEXP; ++e) if (e != e0 && lg[e] > v1){ v1 = lg[e]; e1 = e; }
    float r  = expf(v1 - v0);
    float w0 = 1.f / (1.f + r);
    float w1 = r  / (1.f + r);
    outF[(size_t)NTOK*DDIM + 2*t    ] = (float)e0;
    outF[(size_t)NTOK*DDIM + 2*t + 1] = (float)e1;
    te[t] = make_int2(e0, e1);
    tw[t] = make_float2(w0, w1);
    atomicAdd(&cnt[e0], 1);
    atomicAdd(&cnt[e1], 1);
  }
}

// meta: [0:8) cnt | [8:16) offs | [16:24) cur | [24] ntiles | [32:72) tileE | [72:112) tileM
__global__ void scan_kernel(int* __restrict__ meta){
  if (threadIdx.x == 0){
    int s = 0, nt = 0;
    for (int e = 0; e < EEXP; ++e){
      meta[8+e] = s;
      int c = meta[e];
      int tiles = (c + 255) >> 8;
      for (int i = 0; i < tiles; ++i){ meta[32+nt] = e; meta[72+nt] = i * 256; ++nt; }
      s += (c + 255) & ~255;
    }
    meta[24] = nt;
  }
}

__global__ __launch_bounds__(256) void scatter_kernel(const int2* __restrict__ te,
    const int* __restrict__ offs, int* __restrict__ cur,
    int* __restrict__ tokp, int* __restrict__ pidx){
  int t = blockIdx.x * blockDim.x + threadIdx.x;
  if (t >= NTOK) return;
  int2 e = te[t];
  int p0 = offs[e.x] + atomicAdd(&cur[e.x], 1);
  tokp[p0] = t; pidx[2*t] = p0;
  int p1 = offs[e.y] + atomicAdd(&cur[e.y], 1);
  tokp[p1] = t; pidx[2*t+1] = p1;
}

// ---- gather x rows into compact pair order, pre-swizzled (chunk c <- src chunk c^(row&7)) ----
__global__ __launch_bounds__(256) void gather_x_kernel(const short* __restrict__ xb,
    const int* __restrict__ tokp, short* __restrict__ xg){
  const int rowp = blockIdx.x * 4 + (threadIdx.x >> 6);
  const int l = threadIdx.x & 63;
  const short* src = xb + (size_t)tokp[rowp] * DDIM;
  short* dst = xg + (size_t)rowp * DDIM;
#pragma unroll
  for (int p = 0; p < 2; ++p){
    int c = p * 64 + l;
    int cs = (c & ~7) | ((c ^ rowp) & 7);
    *(short8*)(dst + c * 8) = *(const short8*)(src + cs * 8);
  }
}

// ---- grouped GEMM: 256x256xBK64, 8 waves, 8-phase quadrant schedule (T3+T4+T5) ----
// PHASE 1: h = GELU(xg @ w1b^T + b1)  -> bf16, pre-swizzled, coalesced short8 stores
// PHASE 2: y[ks] = h @ w2b^T (K-split halves, unweighted) -> bf16, linear, coalesced
template<int PHASE, int KDIM, int NDIM, int KSPLIT>
__global__ __launch_bounds__(512, 1) void moe_gemm(
    const short* __restrict__ Ab, const short* __restrict__ Wb,
    const float* __restrict__ bias, const int* __restrict__ meta,
    short* __restrict__ O0, short* __restrict__ O1){
  constexpr int NB = NDIM / BN;
  constexpr int KLEN = KDIM / KSPLIT;
  constexpr int NK = KLEN / BK;
  const int cpx = gridDim.x >> 3;
  const int lid = (blockIdx.x & 7) * cpx + (blockIdx.x >> 3);
  const int tile = lid % MAXT;
  const int rest = lid / MAXT;
  if (tile >= meta[24]) return;
  const int n0 = (rest % NB) * BN;
  const int ks = rest / NB;
  const int e   = meta[32 + tile];
  const int m0  = meta[72 + tile];
  const int cnt = meta[e];
  const int off = meta[8 + e];
  const int mrows = min(BM, cnt - m0);
  const int kbase = ks * KLEN;
  short* O = ks ? O1 : O0;

  __shared__ __align__(16) short SMEM[4][BM * BK];   // A: [0],[1]  B: [2],[3]; 128KB

  const int tid  = threadIdx.x;
  const int lane = tid & 63;
  const int wid  = tid >> 6;
  const int wr   = wid >> 2;   // 0..1 -> 128 rows
  const int wc   = wid & 3;    // 0..3 -> 64 cols

  const short* wE = Wb + (size_t)e * NDIM * KDIM;
  size_t aSrc[4], bSrc[4]; int ldsOff[4];
#pragma unroll
  for (int s = 0; s < 4; ++s){
    const int rb = wid * 8 + s * 64;
    ldsOff[s] = rb * BK;                        // wave-uniform; HW adds lane*16B
    const int r = rb + (lane >> 3);
    aSrc[s] = (size_t)(off + m0 + r) * KDIM + kbase + (lane & 7) * 8;  // pre-swizzled
    bSrc[s] = (size_t)(n0 + r) * KDIM + kbase + (lane & 7) * 8;        // pre-swizzled
  }

  f32x4 acc[8][4];
#pragma unroll
  for (int ii = 0; ii < 8; ++ii)
#pragma unroll
    for (int j = 0; j < 4; ++j) acc[ii][j] = (f32x4){0.f, 0.f, 0.f, 0.f};

  // one K-tile = 4 quadrant phases; stages for tile t+1 at q0(A0) q1(A1) q2(B0+B1);
  // vmcnt(0) folded into q3's closing barrier (youngest load ~2 phases old).
  auto TILE = [&](int t, bool stage_next){
    const int buf = t & 1, nb = buf ^ 1;
    const short* As = SMEM[buf];
    const short* Bs = SMEM[2 + buf];
    const size_t k1 = (size_t)(t + 1) * BK;
    short8 bfr[4][2];
#pragma unroll
    for (int q = 0; q < 4; ++q){
      if (q == 0){
#pragma unroll
        for (int j = 0; j < 4; ++j){
          const int rB = wc * 64 + j * 16 + (lane & 15);
#pragma unroll
          for (int kk = 0; kk < 2; ++kk){
            const int bc = kk * 64 + (lane >> 4) * 16;
            bfr[j][kk] = *(const short8*)&Bs[rB * BK + ((bc ^ ((rB & 7) << 4)) >> 1)];
          }
        }
      }
      short8 af[2][2];
#pragma unroll
      for (int u = 0; u < 2; ++u){
        const int rA = wr * 128 + (2*q + u) * 16 + (lane & 15);
#pragma unroll
        for (int kk = 0; kk < 2; ++kk){
          const int bc = kk * 64 + (lane >> 4) * 16;
          af[u][kk] = *(const short8*)&As[rA * BK + ((bc ^ ((rA & 7) << 4)) >> 1)];
        }
      }
      if (stage_next){
        if (q == 0){
          gload16(Ab + aSrc[0] + k1, &SMEM[nb][ldsOff[0]]);
          gload16(Ab + aSrc[1] + k1, &SMEM[nb][ldsOff[1]]);
        } else if (q == 1){
          gload16(Ab + aSrc[2] + k1, &SMEM[nb][ldsOff[2]]);
          gload16(Ab + aSrc[3] + k1, &SMEM[nb][ldsOff[3]]);
        } else if (q == 2){
#pragma unroll
          for (int s = 0; s < 4; ++s)
            gload16(wE + bSrc[s] + k1, &SMEM[2 + nb][ldsOff[s]]);
        }
      }
      BAR();                                   // phase barrier: reads ready, roles split
      __builtin_amdgcn_s_setprio(1);
#pragma unroll
      for (int u = 0; u < 2; ++u)
#pragma unroll
        for (int j = 0; j < 4; ++j)
#pragma unroll
          for (int kk = 0; kk < 2; ++kk)
            acc[2*q + u][j] = __builtin_amdgcn_mfma_f32_16x16x32_bf16(
                af[u][kk], bfr[j][kk], acc[2*q + u][j], 0, 0, 0);
      __builtin_amdgcn_s_setprio(0);
      if (q == 3 && stage_next)
        asm volatile("s_waitcnt vmcnt(0)" ::: "memory");  // tile t+1 landed
      BAR();
    }
  };

  // prologue: stage tile 0, drain, go
#pragma unroll
  for (int s = 0; s < 4; ++s) gload16(Ab + aSrc[s], &SMEM[0][ldsOff[s]]);
#pragma unroll
  for (int s = 0; s < 4; ++s) gload16(wE + bSrc[s], &SMEM[2][ldsOff[s]]);
  asm volatile("s_waitcnt vmcnt(0)" ::: "memory");
  BAR();
  for (int t = 0; t < NK - 1; ++t) TILE(t, true);
  TILE(NK - 1, false);

  // ---- epilogue: acc -> LDS (bank-swizzled bf16 256x256 tile) -> coalesced stores ----
  short* T = &SMEM[0][0];
#pragma unroll
  for (int j = 0; j < 4; ++j){
    const int n = n0 + wc * 64 + j * 16 + (lane & 15);
    const float bv = (PHASE == 1) ? bias[(size_t)e * NDIM + n] : 0.f;
#pragma unroll
    for (int ii = 0; ii < 8; ++ii){
#pragma unroll
      for (int q = 0; q < 4; ++q){
        const int r = wr * 128 + ii * 16 + (lane >> 4) * 4 + q;
        const int c = wc * 64 + j * 16 + (lane & 15);
        float v = acc[ii][j][q];
        if (PHASE == 1){
          v += bv;
          // tanh-GELU (max err ~1e-3, threshold 0.14): v*sigmoid(1.5957691v + 0.0713548v^3)
          float u2 = v * (1.5957691216057308f + 0.07135481627014317f * v * v);
          v = v / (1.f + __expf(-u2));
        }
        T[r * 256 + (c ^ ((r & 7) << 3))] = (short)f2bf(v);
      }
    }
  }
  __syncthreads();
  {
    const int r = tid >> 1;
    const int key = r & 7;
    const size_t rowb = (size_t)(off + m0 + r) * NDIM + n0;
#pragma unroll
    for (int c8 = 0; c8 < 16; ++c8){
      const int pc = (tid & 1) * 16 + (c8 ^ key);          // phys chunk (bank-spread read)
      short8 v = *(const short8*)&T[r * 256 + pc * 8];
      const int gcc = (PHASE == 1) ? pc : ((tid & 1) * 16 + c8);
      if (r < mrows) *(short8*)&O[rowb + gcc * 8] = v;
    }
  }
}

// ---- combine: out[t] = w0*(y0[p0]+y1[p0]+b2[e0]) + w1*(y0[p1]+y1[p1]+b2[e1]) ----
__global__ __launch_bounds__(256) void combine_kernel(
    const short* __restrict__ y0, const short* __restrict__ y1,
    const int2* __restrict__ te, const float2* __restrict__ tw,
    const int* __restrict__ pidx, const float* __restrict__ b2,
    float* __restrict__ outF){
  const int t = blockIdx.x;
  const int d = threadIdx.x * 4;
  int2 e = te[t]; float2 w = tw[t];
  int p0 = pidx[2*t], p1 = pidx[2*t+1];
  short4v a0 = *(const short4v*)&y0[(size_t)p0 * DDIM + d];
  short4v a1 = *(const short4v*)&y1[(size_t)p0 * DDIM + d];
  short4v c0 = *(const short4v*)&y0[(size_t)p1 * DDIM + d];
  short4v c1 = *(const short4v*)&y1[(size_t)p1 * DDIM + d];
  f32x4 b0 = *(const f32x4*)&b2[(size_t)e.x * DDIM + d];
  f32x4 b1 = *(const f32x4*)&b2[(size_t)e.y * DDIM + d];
  f32x4 o;
#pragma unroll
  for (int q = 0; q < 4; ++q){
    float s0 = bf2f(a0[q]) + bf2f(a1[q]) + b0[q];
    float s1 = bf2f(c0[q]) + bf2f(c1[q]) + b1[q];
    o[q] = w.x * s0 + w.y * s1;
  }
  *(f32x4*)&outF[(size_t)t * DDIM + d] = o;
}

extern "C" void kernel_launch(void* const* d_in, const int* in_sizes, int n_in,
                              void* d_out, int out_size, void* d_ws, size_t ws_size,
                              hipStream_t stream){
  const float* x  = (const float*)d_in[0];
  const float* gw = (const float*)d_in[1];
  const float* gb = (const float*)d_in[2];
  const float* w1 = (const float*)d_in[3];
  const float* b1 = (const float*)d_in[4];
  const float* w2 = (const float*)d_in[5];
  const float* b2 = (const float*)d_in[6];
  float* outF = (float*)d_out;

  char* p = (char*)d_ws;
  short* xb = (short*)p;  p += (size_t)NTOK * DDIM * 2;          // 8.4 MB
  short* xg = (short*)p;  p += (size_t)NPAIR_PAD * DDIM * 2;     // 21 MB; reused as y0
  short* h  = (short*)p;  p += (size_t)NPAIR_PAD * HDIM * 2;     // 83.9 MB
  short* wb = (short*)p;  p += (size_t)EEXP * HDIM * DDIM * 2;   // 67.1 MB (w1b then w2b)
  short* y1 = (short*)p;  p += (size_t)NPAIR_PAD * DDIM * 2;     // 21 MB
  int*   tokp = (int*)p;  p += (size_t)NPAIR_PAD * 4;
  int*   pidx = (int*)p;  p += (size_t)2 * NTOK * 4;
  int2*  te   = (int2*)p; p += (size_t)NTOK * 8;
  float2* tw  = (float2*)p; p += (size_t)NTOK * 8;
  int* meta = (int*)p;
  short* y0 = xg;

  hipMemsetAsync(meta, 0, 24 * sizeof(int), stream);
  hipMemsetAsync(tokp, 0, (size_t)NPAIR_PAD * 4, stream);
  gate_kernel<<<NTOK / 4, 256, 0, stream>>>(x, gw, gb, outF, xb, te, tw, meta);
  scan_kernel<<<1, 64, 0, stream>>>(meta);
  scatter_kernel<<<(NTOK + 255) / 256, 256, 0, stream>>>(te, meta + 8, meta + 16, tokp, pidx);
  gather_x_kernel<<<NPAIR_PAD / 4, 256, 0, stream>>>(xb, tokp, xg);
  convert_w_kernel<<<16384, 256, 0, stream>>>(w1, wb, 10);
  moe_gemm<1, DDIM, HDIM, 1><<<MAXT * (HDIM / BN), 512, 0, stream>>>(
      xg, wb, b1, meta, h, h);
  convert_w_kernel<<<16384, 256, 0, stream>>>(w2, wb, 12);
  moe_gemm<2, HDIM, DDIM, 2><<<MAXT * (DDIM / BN) * 2, 512, 0, stream>>>(
      h, wb, nullptr, meta, y0, y1);
  combine_kernel<<<NTOK, 256, 0, stream>>>(y0, y1, te, tw, pidx, b2, outF);
}

// Round 7
// 507.162 us; speedup vs baseline: 1.6793x; 1.0047x over previous
//
#include <hip/hip_runtime.h>
#include <hip/hip_bf16.h>
#include <math.h>

#define NTOK 4096   // B*S
#define DDIM 1024
#define HDIM 4096
#define EEXP 8
#define NPAIR_PAD (2*NTOK + EEXP*256)   // 10240 (256-padded per-expert segments)
#define MAXT (NPAIR_PAD / 256)          // 40 max m-tiles

#define BM 256
#define BN 256
#define BK 64

typedef __attribute__((ext_vector_type(8))) short short8;
typedef __attribute__((ext_vector_type(4))) short short4v;
typedef __attribute__((ext_vector_type(4))) float f32x4;

static __device__ __forceinline__ unsigned short f2bf(float f){
  unsigned int u = __float_as_uint(f);
  u += 0x7FFFu + ((u >> 16) & 1u);
  return (unsigned short)(u >> 16);
}
static __device__ __forceinline__ float bf2f(short s){
  return __uint_as_float(((unsigned int)(unsigned short)s) << 16);
}
static __device__ __forceinline__ void gload16(const void* g, void* l){
  __builtin_amdgcn_global_load_lds(
      (const __attribute__((address_space(1))) void*)g,
      (__attribute__((address_space(3))) void*)l, 16, 0, 0);
}
static __device__ __forceinline__ void BAR(){
  asm volatile("" ::: "memory");
  __builtin_amdgcn_s_barrier();
  asm volatile("" ::: "memory");
}

// ---- w (f32) -> wb (bf16, pre-swizzled: dest 16B chunk c holds src chunk (c&~7)|((c^row)&7)) ----
__global__ __launch_bounds__(256) void convert_w_kernel(const float* __restrict__ w,
    short* __restrict__ wb, int klog2){
  const int cshift = klog2 - 3;
  size_t i = (size_t)blockIdx.x * 256 + threadIdx.x;
  size_t n = i >> cshift;
  int c = (int)(i & ((1u << cshift) - 1u));
  int csw = (c & ~7) | ((c ^ (int)n) & 7);
  const float* src = w + (n << klog2) + (size_t)csw * 8;
  f32x4 a = ((const f32x4*)src)[0];
  f32x4 b = ((const f32x4*)src)[1];
  short8 o;
#pragma unroll
  for (int j = 0; j < 4; ++j){ o[j] = (short)f2bf(a[j]); o[j+4] = (short)f2bf(b[j]); }
  *(short8*)(wb + (n << klog2) + (size_t)c * 8) = o;
}

// ---- gate: logits, top-2, softmax; emits xb (bf16 x) and 'selected' tail ----
__global__ __launch_bounds__(256) void gate_kernel(const float* __restrict__ x,
    const float* __restrict__ gw, const float* __restrict__ gb,
    float* __restrict__ outF, short* __restrict__ xb,
    int2* __restrict__ te, float2* __restrict__ tw, int* __restrict__ cnt){
  const int t = blockIdx.x * 4 + (threadIdx.x >> 6);
  const int l = threadIdx.x & 63;
  const f32x4* xr = (const f32x4*)(x + (size_t)t * DDIM);
  f32x4 xv[4];
#pragma unroll
  for (int j = 0; j < 4; ++j) xv[j] = xr[l + 64*j];
#pragma unroll
  for (int j = 0; j < 4; ++j){
    short4v o;
#pragma unroll
    for (int q = 0; q < 4; ++q) o[q] = (short)f2bf(xv[j][q]);
    ((short4v*)(xb + (size_t)t * DDIM))[l + 64*j] = o;
  }
  float acc[EEXP];
#pragma unroll
  for (int e = 0; e < EEXP; ++e) acc[e] = 0.f;
#pragma unroll
  for (int j = 0; j < 4; ++j){
#pragma unroll
    for (int e = 0; e < EEXP; ++e){
      f32x4 gv = ((const f32x4*)(gw + (size_t)e*DDIM))[l + 64*j];
      acc[e] += xv[j][0]*gv[0] + xv[j][1]*gv[1] + xv[j][2]*gv[2] + xv[j][3]*gv[3];
    }
  }
#pragma unroll
  for (int e = 0; e < EEXP; ++e){
#pragma unroll
    for (int off = 32; off > 0; off >>= 1) acc[e] += __shfl_xor(acc[e], off);
  }
  if (l == 0){
    float lg[EEXP];
#pragma unroll
    for (int e = 0; e < EEXP; ++e) lg[e] = acc[e] + gb[e];
    int e0 = 0; float v0 = lg[0];
#pragma unroll
    for (int e = 1; e < EEXP; ++e) if (lg[e] > v0){ v0 = lg[e]; e0 = e; }
    int e1 = -1; float v1 = -1e30f;
#pragma unroll
    for (int e = 0; e < EEXP; ++e) if (e != e0 && lg[e] > v1){ v1 = lg[e]; e1 = e; }
    float r  = expf(v1 - v0);
    float w0 = 1.f / (1.f + r);
    float w1 = r  / (1.f + r);
    outF[(size_t)NTOK*DDIM + 2*t    ] = (float)e0;
    outF[(size_t)NTOK*DDIM + 2*t + 1] = (float)e1;
    te[t] = make_int2(e0, e1);
    tw[t] = make_float2(w0, w1);
    atomicAdd(&cnt[e0], 1);
    atomicAdd(&cnt[e1], 1);
  }
}

// meta: [0:8) cnt | [8:16) offs | [16:24) cur | [24] ntiles | [32:72) tileE | [72:112) tileM
__global__ void scan_kernel(int* __restrict__ meta){
  if (threadIdx.x == 0){
    int s = 0, nt = 0;
    for (int e = 0; e < EEXP; ++e){
      meta[8+e] = s;
      int c = meta[e];
      int tiles = (c + 255) >> 8;
      for (int i = 0; i < tiles; ++i){ meta[32+nt] = e; meta[72+nt] = i * 256; ++nt; }
      s += (c + 255) & ~255;
    }
    meta[24] = nt;
  }
}

__global__ __launch_bounds__(256) void scatter_kernel(const int2* __restrict__ te,
    const int* __restrict__ offs, int* __restrict__ cur,
    int* __restrict__ tokp, int* __restrict__ pidx){
  int t = blockIdx.x * blockDim.x + threadIdx.x;
  if (t >= NTOK) return;
  int2 e = te[t];
  int p0 = offs[e.x] + atomicAdd(&cur[e.x], 1);
  tokp[p0] = t; pidx[2*t] = p0;
  int p1 = offs[e.y] + atomicAdd(&cur[e.y], 1);
  tokp[p1] = t; pidx[2*t+1] = p1;
}

// ---- gather x rows into compact pair order, pre-swizzled (chunk c <- src chunk c^(row&7)) ----
__global__ __launch_bounds__(256) void gather_x_kernel(const short* __restrict__ xb,
    const int* __restrict__ tokp, short* __restrict__ xg){
  const int rowp = blockIdx.x * 4 + (threadIdx.x >> 6);
  const int l = threadIdx.x & 63;
  const short* src = xb + (size_t)tokp[rowp] * DDIM;
  short* dst = xg + (size_t)rowp * DDIM;
#pragma unroll
  for (int p = 0; p < 2; ++p){
    int c = p * 64 + l;
    int cs = (c & ~7) | ((c ^ rowp) & 7);
    *(short8*)(dst + c * 8) = *(const short8*)(src + cs * 8);
  }
}

// ---- grouped GEMM: 256x256xBK64, 8 waves, counted-vmcnt (never <8) + phase interleave ----
// PHASE 1: h = GELU(xg @ w1b^T + b1)  -> bf16, pre-swizzled, coalesced short8 stores
// PHASE 2: y[ks] = h @ w2b^T (K-split, unweighted) -> bf16, linear, coalesced
template<int PHASE, int KDIM, int NDIM, int KSPLIT>
__global__ __launch_bounds__(512, 1) void moe_gemm(
    const short* __restrict__ Ab, const short* __restrict__ Wb,
    const float* __restrict__ bias, const int* __restrict__ meta,
    short* __restrict__ O0, short* __restrict__ O1,
    short* __restrict__ O2, short* __restrict__ O3){
  constexpr int NB = NDIM / BN;
  constexpr int KLEN = KDIM / KSPLIT;
  constexpr int NK = KLEN / BK;
  const int cpx = gridDim.x >> 3;
  const int lid = (blockIdx.x & 7) * cpx + (blockIdx.x >> 3);
  const int tile = lid % MAXT;
  const int rest = lid / MAXT;
  if (tile >= meta[24]) return;
  const int n0 = (rest % NB) * BN;
  const int ks = rest / NB;
  const int e   = meta[32 + tile];
  const int m0  = meta[72 + tile];
  const int cnt = meta[e];
  const int off = meta[8 + e];
  const int mrows = min(BM, cnt - m0);
  const int kbase = ks * KLEN;
  short* O = (ks == 0) ? O0 : (ks == 1) ? O1 : (ks == 2) ? O2 : O3;

  __shared__ __align__(16) short SMEM[4][BM * BK];   // A: [0],[1]  B: [2],[3]; 128KB

  const int tid  = threadIdx.x;
  const int lane = tid & 63;
  const int wid  = tid >> 6;
  const int wr   = wid >> 2;   // 0..1 -> 128 rows
  const int wc   = wid & 3;    // 0..3 -> 64 cols

  const short* wE = Wb + (size_t)e * NDIM * KDIM;
  size_t aSrc[4], bSrc[4]; int ldsOff[4];
#pragma unroll
  for (int s = 0; s < 4; ++s){
    const int rb = wid * 8 + s * 64;
    ldsOff[s] = rb * BK;                        // wave-uniform; HW adds lane*16B
    const int r = rb + (lane >> 3);
    aSrc[s] = (size_t)(off + m0 + r) * KDIM + kbase + (lane & 7) * 8;  // pre-swizzled
    bSrc[s] = (size_t)(n0 + r) * KDIM + kbase + (lane & 7) * 8;        // pre-swizzled
  }

  f32x4 acc[8][4];
#pragma unroll
  for (int ii = 0; ii < 8; ++ii)
#pragma unroll
    for (int j = 0; j < 4; ++j) acc[ii][j] = (f32x4){0.f, 0.f, 0.f, 0.f};

  auto STAGE = [&](int buf, int t){
    const size_t k0 = (size_t)t * BK;
#pragma unroll
    for (int s = 0; s < 4; ++s) gload16(Ab + aSrc[s] + k0, &SMEM[buf][ldsOff[s]]);
#pragma unroll
    for (int s = 0; s < 4; ++s) gload16(wE + bSrc[s] + k0, &SMEM[2 + buf][ldsOff[s]]);
  };

  // prologue: stage tile 0 only; loop keeps >=8 loads in flight (counted vmcnt, T4)
  STAGE(0, 0);
  for (int t = 0; t < NK; ++t){
    const int buf = t & 1;
    if (t + 1 < NK){
      STAGE(buf ^ 1, t + 1);                           // 8 loads; 4-phase flight window
      asm volatile("s_waitcnt vmcnt(8)" ::: "memory"); // oldest 8 (= tile t) landed
    } else {
      asm volatile("s_waitcnt vmcnt(0)" ::: "memory");
    }
    BAR();                                             // all waves' tile-t loads landed
    const short* As = SMEM[buf];
    const short* Bs = SMEM[2 + buf];
    short8 bfr[4][2];
#pragma unroll
    for (int q = 0; q < 4; ++q){
      if (q == 0){
#pragma unroll
        for (int j = 0; j < 4; ++j){
          const int rB = wc * 64 + j * 16 + (lane & 15);
#pragma unroll
          for (int kk = 0; kk < 2; ++kk){
            const int bc = kk * 64 + (lane >> 4) * 16;
            bfr[j][kk] = *(const short8*)&Bs[rB * BK + ((bc ^ ((rB & 7) << 4)) >> 1)];
          }
        }
      }
      short8 af[2][2];
#pragma unroll
      for (int u = 0; u < 2; ++u){
        const int rA = wr * 128 + (2*q + u) * 16 + (lane & 15);
#pragma unroll
        for (int kk = 0; kk < 2; ++kk){
          const int bc = kk * 64 + (lane >> 4) * 16;
          af[u][kk] = *(const short8*)&As[rA * BK + ((bc ^ ((rA & 7) << 4)) >> 1)];
        }
      }
      BAR();                                   // phase rhythm: role-split for setprio
      __builtin_amdgcn_s_setprio(1);
#pragma unroll
      for (int u = 0; u < 2; ++u)
#pragma unroll
        for (int j = 0; j < 4; ++j)
#pragma unroll
          for (int kk = 0; kk < 2; ++kk)
            acc[2*q + u][j] = __builtin_amdgcn_mfma_f32_16x16x32_bf16(
                af[u][kk], bfr[j][kk], acc[2*q + u][j], 0, 0, 0);
      __builtin_amdgcn_s_setprio(0);
      BAR();
    }
  }

  // ---- epilogue: acc -> LDS (bank-swizzled bf16 256x256 tile) -> coalesced stores ----
  short* T = &SMEM[0][0];
#pragma unroll
  for (int j = 0; j < 4; ++j){
    const int n = n0 + wc * 64 + j * 16 + (lane & 15);
    const float bv = (PHASE == 1) ? bias[(size_t)e * NDIM + n] : 0.f;
#pragma unroll
    for (int ii = 0; ii < 8; ++ii){
#pragma unroll
      for (int q = 0; q < 4; ++q){
        const int r = wr * 128 + ii * 16 + (lane >> 4) * 4 + q;
        const int c = wc * 64 + j * 16 + (lane & 15);
        float v = acc[ii][j][q];
        if (PHASE == 1){
          v += bv;
          // tanh-GELU (max err ~1e-3, threshold 0.14)
          float u2 = v * (1.5957691216057308f + 0.07135481627014317f * v * v);
          v = v / (1.f + __expf(-u2));
        }
        T[r * 256 + (c ^ ((r & 7) << 3))] = (short)f2bf(v);
      }
    }
  }
  __syncthreads();
  {
    const int r = tid >> 1;
    const int key = r & 7;
    const size_t rowb = (size_t)(off + m0 + r) * NDIM + n0;
#pragma unroll
    for (int c8 = 0; c8 < 16; ++c8){
      const int pc = (tid & 1) * 16 + (c8 ^ key);          // phys chunk (bank-spread read)
      short8 v = *(const short8*)&T[r * 256 + pc * 8];
      const int gcc = (PHASE == 1) ? pc : ((tid & 1) * 16 + c8);
      if (r < mrows) *(short8*)&O[rowb + gcc * 8] = v;
    }
  }
}

// ---- combine: out[t] = w0*(sum_ks y[ks][p0]+b2[e0]) + w1*(sum_ks y[ks][p1]+b2[e1]) ----
template<int KS>
__global__ __launch_bounds__(256) void combine_kernel(
    const short* __restrict__ y0, const short* __restrict__ y1,
    const short* __restrict__ y2, const short* __restrict__ y3,
    const int2* __restrict__ te, const float2* __restrict__ tw,
    const int* __restrict__ pidx, const float* __restrict__ b2,
    float* __restrict__ outF){
  const int t = blockIdx.x;
  const int d = threadIdx.x * 4;
  int2 e = te[t]; float2 w = tw[t];
  int p0 = pidx[2*t], p1 = pidx[2*t+1];
  const short* ys[4] = {y0, y1, y2, y3};
  float s0[4] = {0.f,0.f,0.f,0.f}, s1[4] = {0.f,0.f,0.f,0.f};
#pragma unroll
  for (int k = 0; k < KS; ++k){
    short4v a = *(const short4v*)&ys[k][(size_t)p0 * DDIM + d];
    short4v c = *(const short4v*)&ys[k][(size_t)p1 * DDIM + d];
#pragma unroll
    for (int q = 0; q < 4; ++q){ s0[q] += bf2f(a[q]); s1[q] += bf2f(c[q]); }
  }
  f32x4 b0 = *(const f32x4*)&b2[(size_t)e.x * DDIM + d];
  f32x4 b1 = *(const f32x4*)&b2[(size_t)e.y * DDIM + d];
  f32x4 o;
#pragma unroll
  for (int q = 0; q < 4; ++q)
    o[q] = w.x * (s0[q] + b0[q]) + w.y * (s1[q] + b1[q]);
  *(f32x4*)&outF[(size_t)t * DDIM + d] = o;
}

extern "C" void kernel_launch(void* const* d_in, const int* in_sizes, int n_in,
                              void* d_out, int out_size, void* d_ws, size_t ws_size,
                              hipStream_t stream){
  const float* x  = (const float*)d_in[0];
  const float* gw = (const float*)d_in[1];
  const float* gb = (const float*)d_in[2];
  const float* w1 = (const float*)d_in[3];
  const float* b1 = (const float*)d_in[4];
  const float* w2 = (const float*)d_in[5];
  const float* b2 = (const float*)d_in[6];
  float* outF = (float*)d_out;

  char* p = (char*)d_ws;
  short* xb = (short*)p;  p += (size_t)NTOK * DDIM * 2;          // 8.4 MB
  short* xg = (short*)p;  p += (size_t)NPAIR_PAD * DDIM * 2;     // 21 MB; reused as y0
  short* h  = (short*)p;  p += (size_t)NPAIR_PAD * HDIM * 2;     // 83.9 MB
  short* wb = (short*)p;  p += (size_t)EEXP * HDIM * DDIM * 2;   // 67.1 MB (w1b then w2b)
  short* y1 = (short*)p;  p += (size_t)NPAIR_PAD * DDIM * 2;     // 21 MB
  int*   tokp = (int*)p;  p += (size_t)NPAIR_PAD * 4;
  int*   pidx = (int*)p;  p += (size_t)2 * NTOK * 4;
  int2*  te   = (int2*)p; p += (size_t)NTOK * 8;
  float2* tw  = (float2*)p; p += (size_t)NTOK * 8;
  int* meta = (int*)p;    p += 1024;
  short* y2 = (short*)p;  p += (size_t)NPAIR_PAD * DDIM * 2;     // 21 MB (optional)
  short* y3 = (short*)p;  p += (size_t)NPAIR_PAD * DDIM * 2;     // 21 MB (optional)
  short* y0 = xg;
  const bool split4 = ws_size >= (size_t)(p - (char*)d_ws);      // enough scratch for 4 partials?

  hipMemsetAsync(meta, 0, 24 * sizeof(int), stream);
  hipMemsetAsync(tokp, 0, (size_t)NPAIR_PAD * 4, stream);
  gate_kernel<<<NTOK / 4, 256, 0, stream>>>(x, gw, gb, outF, xb, te, tw, meta);
  scan_kernel<<<1, 64, 0, stream>>>(meta);
  scatter_kernel<<<(NTOK + 255) / 256, 256, 0, stream>>>(te, meta + 8, meta + 16, tokp, pidx);
  gather_x_kernel<<<NPAIR_PAD / 4, 256, 0, stream>>>(xb, tokp, xg);
  convert_w_kernel<<<16384, 256, 0, stream>>>(w1, wb, 10);
  moe_gemm<1, DDIM, HDIM, 1><<<MAXT * (HDIM / BN), 512, 0, stream>>>(
      xg, wb, b1, meta, h, h, h, h);
  convert_w_kernel<<<16384, 256, 0, stream>>>(w2, wb, 12);
  if (split4){
    moe_gemm<2, HDIM, DDIM, 4><<<MAXT * (DDIM / BN) * 4, 512, 0, stream>>>(
        h, wb, nullptr, meta, y0, y1, y2, y3);
    combine_kernel<4><<<NTOK, 256, 0, stream>>>(y0, y1, y2, y3, te, tw, pidx, b2, outF);
  } else {
    moe_gemm<2, HDIM, DDIM, 2><<<MAXT * (DDIM / BN) * 2, 512, 0, stream>>>(
        h, wb, nullptr, meta, y0, y1, y1, y1);
    combine_kernel<2><<<NTOK, 256, 0, stream>>>(y0, y1, y1, y1, te, tw, pidx, b2, outF);
  }
}